// Round 1
// baseline (864.119 us; speedup 1.0000x reference)
//
#include <hip/hip_runtime.h>
#include <cstdint>
#include <cmath>

// Problem constants (B,N,D,W from reference)
#define BB  4
#define NN  4096
#define DD  256
#define HH  1024
#define KK  15
#define PADL 14          // 2*W left pad
#define TM1 16           // tokens per block, kernel 1
#define TM2 8            // tokens per block, kernel 2
#define EPSLN 1e-5f

__device__ __forceinline__ void wave_red2(float& s, float& s2) {
#pragma unroll
  for (int off = 32; off > 0; off >>= 1) {
    s  += __shfl_xor(s,  off, 64);
    s2 += __shfl_xor(s2, off, 64);
  }
}

// ---------------- Kernel 1: causal conv mix + residual + LN1 -> h ----------
__global__ __launch_bounds__(256) void k_mix_ln1(
    const float* __restrict__ x, const float* __restrict__ w_mix,
    const float* __restrict__ b_mix, const float* __restrict__ g1,
    const float* __restrict__ b1, float* __restrict__ h)
{
  const int d = threadIdx.x;                       // output channel
  const long tok0 = (long)blockIdx.x * TM1;        // global row (blocks never straddle batches: 16 | 4096)
  const int n0 = (int)(tok0 & (NN - 1));           // position within batch

  __shared__ float xs[TM1 + PADL][DD];             // rows n0-14 .. n0+15  (30 KB)
  __shared__ float redS[4][TM1], redS2[4][TM1];

#pragma unroll
  for (int r = 0; r < TM1 + PADL; ++r) {
    const int n = n0 - PADL + r;
    xs[r][d] = (n >= 0) ? x[(tok0 - PADL + r) * DD + d] : 0.f;
  }
  __syncthreads();

  float acc[TM1];
  const float bm = b_mix[d];
#pragma unroll
  for (int t = 0; t < TM1; ++t) acc[t] = bm;

  for (int c = 0; c < DD; ++c) {
    float xr[TM1 + PADL];
#pragma unroll
    for (int r = 0; r < TM1 + PADL; ++r) xr[r] = xs[r][c];   // LDS broadcast reads
    const float* wp = w_mix + (size_t)c * DD + d;            // w_mix[k][c][d], coalesced over d
#pragma unroll
    for (int k = 0; k < KK; ++k) {
      const float w = wp[(size_t)k * DD * DD];
#pragma unroll
      for (int t = 0; t < TM1; ++t) acc[t] += xr[t + k] * w;
    }
  }

  float yv[TM1];
#pragma unroll
  for (int t = 0; t < TM1; ++t) yv[t] = xs[PADL + t][d] + acc[t];  // residual

  const int wave = d >> 6;
#pragma unroll
  for (int t = 0; t < TM1; ++t) {
    float s = yv[t], s2 = yv[t] * yv[t];
    wave_red2(s, s2);
    if ((d & 63) == 0) { redS[wave][t] = s; redS2[wave][t] = s2; }
  }
  __syncthreads();

  const float G = g1[d], Bv = b1[d];
#pragma unroll
  for (int t = 0; t < TM1; ++t) {
    const float s  = redS[0][t] + redS[1][t] + redS[2][t] + redS[3][t];
    const float s2 = redS2[0][t] + redS2[1][t] + redS2[2][t] + redS2[3][t];
    const float mu  = s * (1.0f / DD);
    const float var = s2 * (1.0f / DD) - mu * mu;
    const float inv = rsqrtf(var + EPSLN);
    h[(tok0 + t) * DD + d] = (yv[t] - mu) * inv * G + Bv;
  }
}

// ------------- Kernel 2: FF1 + exact gelu + FF2 + residual + LN2 -----------
__global__ __launch_bounds__(256) void k_ffn_ln2(
    const float* __restrict__ h, const float* __restrict__ w1,
    const float* __restrict__ bf1, const float* __restrict__ w2,
    const float* __restrict__ bf2, const float* __restrict__ g2,
    const float* __restrict__ b2, float* __restrict__ out)
{
  const int d = threadIdx.x;
  const long tok0 = (long)blockIdx.x * TM2;

  __shared__ float hs[TM2][DD];          // 8 KB
  __shared__ float as[TM2][HH];          // 32 KB
  __shared__ float redS[4][TM2], redS2[4][TM2];

#pragma unroll
  for (int t = 0; t < TM2; ++t) hs[t][d] = h[(tok0 + t) * DD + d];
  __syncthreads();

  // ---- stage 1: a = h @ w_ff1 + b_ff1 ; thread d owns j = d + 256*jj ----
  float a1[TM2][4];
#pragma unroll
  for (int jj = 0; jj < 4; ++jj) {
    const float bv = bf1[d + 256 * jj];
#pragma unroll
    for (int t = 0; t < TM2; ++t) a1[t][jj] = bv;
  }

  for (int c = 0; c < DD; c += 4) {
    float4 hr[TM2];
#pragma unroll
    for (int t = 0; t < TM2; ++t) hr[t] = *(const float4*)&hs[t][c];
#pragma unroll
    for (int i = 0; i < 4; ++i) {
      const float* wp = w1 + (size_t)(c + i) * HH + d;
      float w[4];
#pragma unroll
      for (int jj = 0; jj < 4; ++jj) w[jj] = wp[256 * jj];
#pragma unroll
      for (int t = 0; t < TM2; ++t) {
        const float hv = (i == 0) ? hr[t].x : (i == 1) ? hr[t].y : (i == 2) ? hr[t].z : hr[t].w;
#pragma unroll
        for (int jj = 0; jj < 4; ++jj) a1[t][jj] += hv * w[jj];
      }
    }
  }

  // exact gelu (reference uses approximate=False -> erf)
#pragma unroll
  for (int jj = 0; jj < 4; ++jj)
#pragma unroll
    for (int t = 0; t < TM2; ++t) {
      const float v = a1[t][jj];
      as[t][d + 256 * jj] = 0.5f * v * (1.0f + erff(v * 0.70710678118654752f));
    }
  __syncthreads();

  // ---- stage 2: ff = gelu(a) @ w_ff2 + b_ff2 ----
  float a2[TM2];
  {
    const float bv = bf2[d];
#pragma unroll
    for (int t = 0; t < TM2; ++t) a2[t] = bv;
  }
  for (int j = 0; j < HH; j += 4) {
    const float* wp = w2 + (size_t)j * DD + d;
    const float w0 = wp[0], w1v = wp[DD], w2v = wp[2 * DD], w3v = wp[3 * DD];
#pragma unroll
    for (int t = 0; t < TM2; ++t) {
      const float4 av = *(const float4*)&as[t][j];
      a2[t] += av.x * w0 + av.y * w1v + av.z * w2v + av.w * w3v;
    }
  }

  // ---- residual + LN2 ----
  float yv[TM2];
#pragma unroll
  for (int t = 0; t < TM2; ++t) yv[t] = hs[t][d] + a2[t];

  const int wave = d >> 6;
#pragma unroll
  for (int t = 0; t < TM2; ++t) {
    float s = yv[t], s2 = yv[t] * yv[t];
    wave_red2(s, s2);
    if ((d & 63) == 0) { redS[wave][t] = s; redS2[wave][t] = s2; }
  }
  __syncthreads();

  const float G = g2[d], Bv = b2[d];
#pragma unroll
  for (int t = 0; t < TM2; ++t) {
    const float s  = redS[0][t] + redS[1][t] + redS[2][t] + redS[3][t];
    const float s2 = redS2[0][t] + redS2[1][t] + redS2[2][t] + redS2[3][t];
    const float mu  = s * (1.0f / DD);
    const float var = s2 * (1.0f / DD) - mu * mu;
    const float inv = rsqrtf(var + EPSLN);
    out[(tok0 + t) * DD + d] = (yv[t] - mu) * inv * G + Bv;
  }
}

extern "C" void kernel_launch(void* const* d_in, const int* in_sizes, int n_in,
                              void* d_out, int out_size, void* d_ws, size_t ws_size,
                              hipStream_t stream) {
  const float* x    = (const float*)d_in[0];
  const float* wmix = (const float*)d_in[1];
  const float* bmix = (const float*)d_in[2];
  const float* g1   = (const float*)d_in[3];
  const float* b1   = (const float*)d_in[4];
  const float* wff1 = (const float*)d_in[5];
  const float* bff1 = (const float*)d_in[6];
  const float* wff2 = (const float*)d_in[7];
  const float* bff2 = (const float*)d_in[8];
  const float* g2   = (const float*)d_in[9];
  const float* b2   = (const float*)d_in[10];
  float* out  = (float*)d_out;
  float* hbuf = (float*)d_ws;                 // R*D fp32 = 16 MB scratch for h

  const int R = BB * NN;                      // 16384 tokens
  k_mix_ln1 <<<R / TM1, 256, 0, stream>>>(x, wmix, bmix, g1, b1, hbuf);
  k_ffn_ln2 <<<R / TM2, 256, 0, stream>>>(hbuf, wff1, bff1, wff2, bff2, g2, b2, out);
}

// Round 2
// 218.333 us; speedup vs baseline: 3.9578x; 3.9578x over previous
//
#include <hip/hip_runtime.h>
#include <cstdint>

// ---------------- problem constants ----------------
#define DD     256
#define HH     1024
#define NNSEQ  4096
#define KDIM   3840          // 15 * 256 (conv-as-GEMM K)
#define NSTEPS 120           // KDIM / 32
#define MT     64            // tokens per block (both GEMM kernels)
#define XROWS  78            // MT + 14 halo rows
#define XPITCH 264           // 256 + 8 pad (bf16 elems); 528 B row = 33*16 -> aligned, 4-bank shift
#define APITCH 136           // 128 + 8 pad; 272 B row -> aligned, 4-bank shift
#define EPSLN  1e-5f

typedef unsigned short u16;
typedef __attribute__((ext_vector_type(8))) short short8;
typedef __attribute__((ext_vector_type(4))) float f32x4;

#define MFMA(a, b, c) __builtin_amdgcn_mfma_f32_16x16x32_bf16(a, b, c, 0, 0, 0)

__device__ __forceinline__ u16 f2bf(float f) {           // RNE fp32 -> bf16
  unsigned u = __float_as_uint(f);
  u += 0x7FFF + ((u >> 16) & 1);
  return (u16)(u >> 16);
}
__device__ __forceinline__ float bf2f(u16 s) { return __uint_as_float(((unsigned)s) << 16); }

// ---------------- pre-pass: fp32 [R][C] -> bf16 [C][R] ----------------
__global__ __launch_bounds__(256) void k_transpose_bf16(
    const float* __restrict__ src, u16* __restrict__ dst, int R, int C)
{
  __shared__ float t[32][33];
  const int tc = blockIdx.x * 32, tr = blockIdx.y * 32;
  const int c = threadIdx.x & 31, r0 = threadIdx.x >> 5;   // 8 rows per pass
#pragma unroll
  for (int i = 0; i < 4; ++i) {
    const int r = r0 + i * 8;
    t[r][c] = src[(size_t)(tr + r) * C + tc + c];
  }
  __syncthreads();
#pragma unroll
  for (int i = 0; i < 4; ++i) {
    const int r = r0 + i * 8;
    dst[(size_t)(tc + r) * R + tr + c] = f2bf(t[c][r]);
  }
}

// ---------------- kernel 1: causal conv (MFMA) + residual + LN1 -> h (bf16) ----
// A[m][kk] = x[tok0+m-14+(kk>>8)][kk&255]  (staged in xs)
// B[kk][d] from wmt[d][kk] (bf16, k-contiguous)
__global__ __launch_bounds__(256) void k_mix_ln1(
    const float* __restrict__ x, const u16* __restrict__ wmt,
    const float* __restrict__ bmix, const float* __restrict__ g1,
    const float* __restrict__ b1, u16* __restrict__ h)
{
  __shared__ u16 xs[XROWS * XPITCH];                 // 41.2 KB
  __shared__ float redS[4][64], redS2[4][64];
  __shared__ float muL[64], invL[64];

  const int tid = threadIdx.x;
  const int w = tid >> 6, l = tid & 63, q = l >> 4, cl = l & 15;
  const long tok0 = (long)blockIdx.x * MT;
  const int n0 = (int)(tok0 & (NNSEQ - 1));          // position within batch (64 | 4096)
  const int nbase = w * 64;                          // wave's 64-col N slice

  // ---- stage x rows [tok0-14, tok0+63] as bf16 into LDS ----
  {
    const int cslot = (tid & 63) * 4;                // 4 floats per thread, 64 slots/row
    for (int r = tid >> 6; r < XROWS; r += 4) {
      const int nloc = n0 - 14 + r;                  // causal zero-pad within batch
      float4 v = make_float4(0.f, 0.f, 0.f, 0.f);
      if (nloc >= 0) v = *(const float4*)&x[(tok0 - 14 + r) * DD + cslot];
      uint2 pk;
      pk.x = (unsigned)f2bf(v.x) | ((unsigned)f2bf(v.y) << 16);
      pk.y = (unsigned)f2bf(v.z) | ((unsigned)f2bf(v.w) << 16);
      *(uint2*)&xs[r * XPITCH + cslot] = pk;
    }
  }
  __syncthreads();

  // ---- accumulators: 4 m-tiles x 4 n-tiles of 16x16, init = b_mix ----
  f32x4 acc[4][4];
#pragma unroll
  for (int nt = 0; nt < 4; ++nt) {
    const float bm = bmix[nbase + nt * 16 + cl];
#pragma unroll
    for (int mt = 0; mt < 4; ++mt) acc[mt][nt] = (f32x4){bm, bm, bm, bm};
  }

  // ---- K loop, double-buffered fragment prefetch ----
  short8 af[2][4], bfr[2][4];
#pragma unroll
  for (int mt = 0; mt < 4; ++mt)
    af[0][mt] = *(const short8*)&xs[(mt * 16 + cl) * XPITCH + q * 8];
#pragma unroll
  for (int nt = 0; nt < 4; ++nt)
    bfr[0][nt] = *(const short8*)&wmt[(size_t)(nbase + nt * 16 + cl) * KDIM + q * 8];

#pragma unroll 2
  for (int s = 0; s < NSTEPS; ++s) {
    const int cur = s & 1, nxt = cur ^ 1;
    if (s + 1 < NSTEPS) {
      const int s1 = s + 1;
      const int xrow = s1 >> 3, c0 = (s1 & 7) * 32;
#pragma unroll
      for (int mt = 0; mt < 4; ++mt)
        af[nxt][mt] = *(const short8*)&xs[(xrow + mt * 16 + cl) * XPITCH + c0 + q * 8];
      const size_t ko = (size_t)(s1 * 32 + q * 8);
#pragma unroll
      for (int nt = 0; nt < 4; ++nt)
        bfr[nxt][nt] = *(const short8*)&wmt[(size_t)(nbase + nt * 16 + cl) * KDIM + ko];
    }
#pragma unroll
    for (int mt = 0; mt < 4; ++mt)
#pragma unroll
      for (int nt = 0; nt < 4; ++nt)
        acc[mt][nt] = MFMA(af[cur][mt], bfr[cur][nt], acc[mt][nt]);
  }

  // ---- residual (fp32 x) ; y kept in acc ----
#pragma unroll
  for (int mt = 0; mt < 4; ++mt)
#pragma unroll
    for (int nt = 0; nt < 4; ++nt) {
      const int col = nbase + nt * 16 + cl;
#pragma unroll
      for (int reg = 0; reg < 4; ++reg) {
        const int row = mt * 16 + q * 4 + reg;
        acc[mt][nt][reg] += x[(tok0 + row) * DD + col];
      }
    }

  // ---- LN1: row sums (wave slice -> 16-lane shuffle -> cross-wave LDS) ----
  float ps[4][4], ps2[4][4];
#pragma unroll
  for (int mt = 0; mt < 4; ++mt)
#pragma unroll
    for (int reg = 0; reg < 4; ++reg) {
      float s = 0.f, s2 = 0.f;
#pragma unroll
      for (int nt = 0; nt < 4; ++nt) { const float y = acc[mt][nt][reg]; s += y; s2 += y * y; }
#pragma unroll
      for (int off = 1; off < 16; off <<= 1) { s += __shfl_xor(s, off, 64); s2 += __shfl_xor(s2, off, 64); }
      ps[mt][reg] = s; ps2[mt][reg] = s2;
    }
  if (cl == 0) {
#pragma unroll
    for (int mt = 0; mt < 4; ++mt)
#pragma unroll
      for (int reg = 0; reg < 4; ++reg) {
        const int row = mt * 16 + q * 4 + reg;
        redS[w][row] = ps[mt][reg]; redS2[w][row] = ps2[mt][reg];
      }
  }
  __syncthreads();
  if (tid < 64) {
    const float s  = redS[0][tid] + redS[1][tid] + redS[2][tid] + redS[3][tid];
    const float s2 = redS2[0][tid] + redS2[1][tid] + redS2[2][tid] + redS2[3][tid];
    const float mu = s * (1.f / DD);
    const float var = s2 * (1.f / DD) - mu * mu;
    muL[tid] = mu; invL[tid] = rsqrtf(var + EPSLN);
  }
  __syncthreads();

#pragma unroll
  for (int nt = 0; nt < 4; ++nt) {
    const int col = nbase + nt * 16 + cl;
    const float gv = g1[col], bv = b1[col];
#pragma unroll
    for (int mt = 0; mt < 4; ++mt)
#pragma unroll
      for (int reg = 0; reg < 4; ++reg) {
        const int row = mt * 16 + q * 4 + reg;
        const float hv = (acc[mt][nt][reg] - muL[row]) * invL[row] * gv + bv;
        h[(tok0 + row) * DD + col] = f2bf(hv);
      }
  }
}

// ---------------- kernel 2: FF1 + gelu + FF2 (chunked over H) + residual + LN2 ----
__global__ __launch_bounds__(256) void k_ffn_ln2(
    const u16* __restrict__ h, const u16* __restrict__ w1t,
    const float* __restrict__ bf1, const u16* __restrict__ w2t,
    const float* __restrict__ bf2, const float* __restrict__ g2,
    const float* __restrict__ b2, float* __restrict__ out)
{
  __shared__ u16 hs[64 * XPITCH];                    // 33.8 KB
  __shared__ u16 asb[64 * APITCH];                   // 17.4 KB (single buffer)
  __shared__ float redS[4][64], redS2[4][64];
  __shared__ float muL[64], invL[64];

  const int tid = threadIdx.x;
  const int w = tid >> 6, l = tid & 63, q = l >> 4, cl = l & 15;
  const long tok0 = (long)blockIdx.x * MT;

  // ---- stage h tile (bf16 copy, padded pitch) ----
  {
    const int row0 = tid >> 5, chunk = tid & 31;     // 16 B per thread, 8 rows/iter
#pragma unroll
    for (int i = 0; i < 8; ++i) {
      const int row = row0 + i * 8;
      const uint4 v = *(const uint4*)&h[(tok0 + row) * DD + chunk * 8];
      *(uint4*)&hs[row * XPITCH + chunk * 8] = v;
    }
  }
  __syncthreads();

  // ---- FF2 accumulators (persist across chunks), init = b_ff2 ----
  f32x4 acc2[4][4];
#pragma unroll
  for (int nt = 0; nt < 4; ++nt) {
    const float bv = bf2[w * 64 + nt * 16 + cl];
#pragma unroll
    for (int mt = 0; mt < 4; ++mt) acc2[mt][nt] = (f32x4){bv, bv, bv, bv};
  }

  for (int c = 0; c < 8; ++c) {                      // 8 chunks of 128 H-cols
    // ---- FF1: rows 0..63 x wave's 32-col slice of this chunk ----
    f32x4 acc1[4][2];
#pragma unroll
    for (int nt = 0; nt < 2; ++nt) {
      const float bv = bf1[c * 128 + w * 32 + nt * 16 + cl];
#pragma unroll
      for (int mt = 0; mt < 4; ++mt) acc1[mt][nt] = (f32x4){bv, bv, bv, bv};
    }
    for (int s = 0; s < 8; ++s) {                    // K = 256
      short8 a[4], b[2];
#pragma unroll
      for (int mt = 0; mt < 4; ++mt)
        a[mt] = *(const short8*)&hs[(mt * 16 + cl) * XPITCH + s * 32 + q * 8];
#pragma unroll
      for (int nt = 0; nt < 2; ++nt)
        b[nt] = *(const short8*)&w1t[(size_t)(c * 128 + w * 32 + nt * 16 + cl) * DD + s * 32 + q * 8];
#pragma unroll
      for (int mt = 0; mt < 4; ++mt)
#pragma unroll
        for (int nt = 0; nt < 2; ++nt)
          acc1[mt][nt] = MFMA(a[mt], b[nt], acc1[mt][nt]);
    }
    // ---- exact gelu, scatter bf16 into asb (A-layout for FF2) ----
#pragma unroll
    for (int mt = 0; mt < 4; ++mt)
#pragma unroll
      for (int nt = 0; nt < 2; ++nt)
#pragma unroll
        for (int reg = 0; reg < 4; ++reg) {
          const float v = acc1[mt][nt][reg];
          const float g = 0.5f * v * (1.f + erff(v * 0.70710678118654752f));
          asb[(mt * 16 + q * 4 + reg) * APITCH + w * 32 + nt * 16 + cl] = f2bf(g);
        }
    __syncthreads();
    // ---- FF2 partial over this chunk's 128 K ----
    for (int s = 0; s < 4; ++s) {
      short8 a[4], b[4];
#pragma unroll
      for (int mt = 0; mt < 4; ++mt)
        a[mt] = *(const short8*)&asb[(mt * 16 + cl) * APITCH + s * 32 + q * 8];
#pragma unroll
      for (int nt = 0; nt < 4; ++nt)
        b[nt] = *(const short8*)&w2t[(size_t)(w * 64 + nt * 16 + cl) * HH + c * 128 + s * 32 + q * 8];
#pragma unroll
      for (int mt = 0; mt < 4; ++mt)
#pragma unroll
        for (int nt = 0; nt < 4; ++nt)
          acc2[mt][nt] = MFMA(a[mt], b[nt], acc2[mt][nt]);
    }
    __syncthreads();                                 // asb reusable next chunk
  }

  // ---- residual (h bf16 from LDS) ; y kept in acc2 ----
#pragma unroll
  for (int mt = 0; mt < 4; ++mt)
#pragma unroll
    for (int nt = 0; nt < 4; ++nt) {
      const int col = w * 64 + nt * 16 + cl;
#pragma unroll
      for (int reg = 0; reg < 4; ++reg) {
        const int row = mt * 16 + q * 4 + reg;
        acc2[mt][nt][reg] += bf2f(hs[row * XPITCH + col]);
      }
    }

  // ---- LN2 ----
  float ps[4][4], ps2[4][4];
#pragma unroll
  for (int mt = 0; mt < 4; ++mt)
#pragma unroll
    for (int reg = 0; reg < 4; ++reg) {
      float s = 0.f, s2 = 0.f;
#pragma unroll
      for (int nt = 0; nt < 4; ++nt) { const float y = acc2[mt][nt][reg]; s += y; s2 += y * y; }
#pragma unroll
      for (int off = 1; off < 16; off <<= 1) { s += __shfl_xor(s, off, 64); s2 += __shfl_xor(s2, off, 64); }
      ps[mt][reg] = s; ps2[mt][reg] = s2;
    }
  if (cl == 0) {
#pragma unroll
    for (int mt = 0; mt < 4; ++mt)
#pragma unroll
      for (int reg = 0; reg < 4; ++reg) {
        const int row = mt * 16 + q * 4 + reg;
        redS[w][row] = ps[mt][reg]; redS2[w][row] = ps2[mt][reg];
      }
  }
  __syncthreads();
  if (tid < 64) {
    const float s  = redS[0][tid] + redS[1][tid] + redS[2][tid] + redS[3][tid];
    const float s2 = redS2[0][tid] + redS2[1][tid] + redS2[2][tid] + redS2[3][tid];
    const float mu = s * (1.f / DD);
    const float var = s2 * (1.f / DD) - mu * mu;
    muL[tid] = mu; invL[tid] = rsqrtf(var + EPSLN);
  }
  __syncthreads();

#pragma unroll
  for (int nt = 0; nt < 4; ++nt) {
    const int col = w * 64 + nt * 16 + cl;
    const float gv = g2[col], bv = b2[col];
#pragma unroll
    for (int mt = 0; mt < 4; ++mt)
#pragma unroll
      for (int reg = 0; reg < 4; ++reg) {
        const int row = mt * 16 + q * 4 + reg;
        out[(tok0 + row) * DD + col] = (acc2[mt][nt][reg] - muL[row]) * invL[row] * gv + bv;
      }
  }
}

// ---------------- launch ----------------
extern "C" void kernel_launch(void* const* d_in, const int* in_sizes, int n_in,
                              void* d_out, int out_size, void* d_ws, size_t ws_size,
                              hipStream_t stream) {
  const float* x    = (const float*)d_in[0];
  const float* wmix = (const float*)d_in[1];   // [3840][256] (= [k][c][d] flattened)
  const float* bmix = (const float*)d_in[2];
  const float* g1   = (const float*)d_in[3];
  const float* b1   = (const float*)d_in[4];
  const float* wff1 = (const float*)d_in[5];   // [256][1024]
  const float* bff1 = (const float*)d_in[6];
  const float* wff2 = (const float*)d_in[7];   // [1024][256]
  const float* bff2 = (const float*)d_in[8];
  const float* g2   = (const float*)d_in[9];
  const float* b2   = (const float*)d_in[10];
  float* out = (float*)d_out;

  u16* wmt = (u16*)d_ws;                 // [256][3840] bf16  (1.97 MB)
  u16* w1t = wmt + 983040;               // [1024][256] bf16  (0.5 MB)
  u16* w2t = w1t + 262144;               // [256][1024] bf16  (0.5 MB)
  u16* hb  = w2t + 262144;               // [16384][256] bf16 (8 MB)

  k_transpose_bf16<<<dim3(8, 120), 256, 0, stream>>>(wmix, wmt, KDIM, DD);
  k_transpose_bf16<<<dim3(32, 8),  256, 0, stream>>>(wff1, w1t, DD, HH);
  k_transpose_bf16<<<dim3(8, 32),  256, 0, stream>>>(wff2, w2t, HH, DD);

  const int R = 4 * NNSEQ;               // 16384 tokens
  k_mix_ln1 <<<R / MT, 256, 0, stream>>>(x, wmt, bmix, g1, b1, hb);
  k_ffn_ln2 <<<R / MT, 256, 0, stream>>>(hb, w1t, bff1, w2t, bff2, g2, b2, out);
}